// Round 14
// baseline (243.703 us; speedup 1.0000x reference)
//
#include <hip/hip_runtime.h>
#include <hip/hip_bf16.h>

#define NNX 256
#define CCX 128
#define HHX 4
#define CHDX 32
#define NIJ (NNX*NNX)

typedef __hip_bfloat16 bf16;
typedef __hip_bfloat162 bf162;
typedef __attribute__((ext_vector_type(8))) short short8v;
typedef __attribute__((ext_vector_type(4))) float float4v;
typedef __attribute__((ext_vector_type(4))) unsigned int uint4v;

__device__ __forceinline__ float4v MFMA(short8v a, short8v b, float4v c){
  return __builtin_amdgcn_mfma_f32_16x16x32_bf16(a, b, c, 0, 0, 0);
}

__device__ __forceinline__ unsigned pk2(float a, float b){
  unsigned short ua = __bfloat16_as_ushort(__float2bfloat16(a));
  unsigned short ub = __bfloat16_as_ushort(__float2bfloat16(b));
  return (unsigned)ua | ((unsigned)ub << 16);
}
__device__ __forceinline__ float ubf(unsigned short u){
  return __bfloat162float(__ushort_as_bfloat16(u));
}

// x [I,J,C] -> out [C,I,J]
__global__ __launch_bounds__(256) void k_tout(const float* __restrict__ x, float* __restrict__ out){
  __shared__ float t[32][33];
  const int i = blockIdx.z, jt = blockIdx.x, ct = blockIdx.y;
  const int tx = threadIdx.x, ty = threadIdx.y;
  #pragma unroll
  for(int k=0;k<32;k+=8){
    t[ty+k][tx] = x[((size_t)i*NNX + jt*32+ty+k)*CCX + ct*32 + tx];
  }
  __syncthreads();
  #pragma unroll
  for(int k=0;k<32;k+=8){
    out[(size_t)(ct*32+ty+k)*NIJ + (size_t)i*NNX + jt*32 + tx] = t[tx][ty+k];
  }
}

// FUSED pass-1 front-end: cmap [C,I,J] tile-transpose + LayerNorm + tb.
// x gets the RAW transposed cmap (residual base); xln/tb2 get the LN outputs.
__global__ __launch_bounds__(256) void k_lntin(const float* __restrict__ cmap,
    const float* __restrict__ w, const float* __restrict__ b,
    const float* __restrict__ wz, float* __restrict__ x,
    bf16* __restrict__ xln, float* __restrict__ tb2){
  __shared__ float t[32][130];
  const int jt = blockIdx.x, i = blockIdx.y;
  const int tx = threadIdx.x, ty = threadIdx.y;   // 32, 8
  #pragma unroll
  for(int kk=0; kk<16; ++kk){
    const int c = kk*8 + ty;
    t[tx][c] = cmap[(size_t)c*NIJ + (size_t)i*NNX + jt*32 + tx];
  }
  __syncthreads();
  const int tid = ty*32 + tx;
  const int row = tid >> 3, cs = tid & 7;        // 32 rows x 8 c-slots
  const int c0 = cs*16;
  float v[16];
  #pragma unroll
  for(int u=0;u<16;++u) v[u] = t[row][c0+u];
  float s=0.f, s2=0.f;
  #pragma unroll
  for(int u=0;u<16;++u){ s += v[u]; s2 += v[u]*v[u]; }
  #pragma unroll
  for(int off=4; off>0; off>>=1){ s += __shfl_xor(s,off); s2 += __shfl_xor(s2,off); }
  const float mu = s*0.0078125f;
  const float var = s2*0.0078125f - mu*mu;
  const float rs = rsqrtf(var+1e-5f);
  const int r = i*NNX + jt*32 + row;
  float a[16];
  #pragma unroll
  for(int u=0;u<16;++u) a[u] = (v[u]-mu)*rs*w[c0+u]+b[c0+u];
  // x = RAW transposed cmap (residual base)
  float* xd = x + (size_t)r*CCX + c0;
  #pragma unroll
  for(int u4=0;u4<4;++u4){
    float4 f4; f4.x=v[u4*4]; f4.y=v[u4*4+1]; f4.z=v[u4*4+2]; f4.w=v[u4*4+3];
    *(float4*)(xd + u4*4) = f4;
  }
  // xln (bf16) = LN output
  bf16* xl = xln + (size_t)r*CCX + c0;
  #pragma unroll
  for(int u8=0;u8<4;++u8){
    uint2 pw; pw.x = pk2(a[u8*4], a[u8*4+1]); pw.y = pk2(a[u8*4+2], a[u8*4+3]);
    *(uint2*)(xl + u8*4) = pw;
  }
  // tb = x_ln @ wz
  float acc[4] = {0.f,0.f,0.f,0.f};
  #pragma unroll
  for(int u=0;u<16;++u){
    #pragma unroll
    for(int hh=0;hh<4;++hh) acc[hh] += a[u]*wz[(c0+u)*4+hh];
  }
  #pragma unroll
  for(int off=4; off>0; off>>=1){
    #pragma unroll
    for(int hh=0;hh<4;++hh) acc[hh] += __shfl_xor(acc[hh], off);
  }
  if(cs==0){
    #pragma unroll
    for(int hh=0;hh<4;++hh) tb2[(size_t)hh*NIJ + r] = acc[hh];
  }
}

// fused LayerNorm + triangle-bias projection for pass 2 (reads x transposed).
template<int TRANS>
__global__ __launch_bounds__(256) void k_lntb(const float* __restrict__ x,
    const float* __restrict__ w, const float* __restrict__ b,
    const float* __restrict__ wz, bf16* __restrict__ xln, float* __restrict__ tb2){
  const int r = blockIdx.x*4 + threadIdx.y;
  const int ii = r>>8, jj = r&255;
  const float* src = x + (size_t)(TRANS ? (jj*NNX+ii) : r)*CCX;
  const int c = threadIdx.x*2;
  float2 v = *(const float2*)(src+c);
  float s = v.x+v.y, s2 = v.x*v.x+v.y*v.y;
  #pragma unroll
  for(int off=32; off>0; off>>=1){ s += __shfl_xor(s,off); s2 += __shfl_xor(s2,off); }
  float mu = s*0.0078125f;
  float var = s2*0.0078125f - mu*mu;
  float rs = rsqrtf(var+1e-5f);
  float a0 = (v.x-mu)*rs*w[c]+b[c];
  float a1 = (v.y-mu)*rs*w[c+1]+b[c+1];
  bf162 hp; hp.x = __float2bfloat16(a0); hp.y = __float2bfloat16(a1);
  *(bf162*)(xln + (size_t)r*CCX + c) = hp;
  float acc[4];
  #pragma unroll
  for(int hh=0;hh<4;++hh) acc[hh] = a0*wz[c*4+hh] + a1*wz[(c+1)*4+hh];
  #pragma unroll
  for(int off=32; off>0; off>>=1){
    #pragma unroll
    for(int hh=0;hh<4;++hh) acc[hh] += __shfl_xor(acc[hh], off);
  }
  if(threadIdx.x==0){
    #pragma unroll
    for(int hh=0;hh<4;++hh) tb2[(size_t)hh*NIJ + r] = acc[hh];
  }
}

// convert+transpose weights: wT[0,512): {wq,wk,wv,wg}^T ; +65536: woT
__global__ __launch_bounds__(256) void k_cvtw(const float* __restrict__ wq,
    const float* __restrict__ wk, const float* __restrict__ wv,
    const float* __restrict__ wg, const float* __restrict__ wo, bf16* __restrict__ wT){
  int idx = blockIdx.x*256 + threadIdx.x;   // 81920
  if(idx < 65536){
    int n = idx >> 7, k = idx & 127;
    const float* W = (n<128)?wq:(n<256)?wk:(n<384)?wv:wg;
    wT[idx] = __float2bfloat16(W[k*CCX + (n&127)]);
  } else {
    int idx2 = idx - 65536;
    int n = idx2 >> 7, k = idx2 & 127;
    wT[idx] = __float2bfloat16(wo[k*CCX + n]);
  }
}

// FUSED projection + attention per (i,h) — r8 structure, LDS dieted to 52KB:
// Qs dropped from 80B-pitch (20KB) to 64B-pitch + 16B-slot XOR swizzle (16KB)
// -> 3 blocks/CU (was 2). Ks keeps 80B pitch (O-bounce holes); Vt unchanged.
// Grid: i = id>>2, h = id&3 (i-major, known-good).
__global__ __launch_bounds__(256,2) void k_fattn(const bf16* __restrict__ xln,
    const bf16* __restrict__ wT, const float* __restrict__ bg,
    const float* __restrict__ tb2, bf16* __restrict__ op){
  __shared__ unsigned short Qs[256*32];      // 16KB  Q rows [q][d], 64B pitch, slot-swizzled
  __shared__ unsigned short Ks[256*40];      // 20KB  K rows [k][d] + O-bounce holes
  __shared__ unsigned short Vt[32*256];      // 16KB  V^T [d][kappa], XOR-swizzled
  const int id = blockIdx.x;
  const int i = id >> 2, h = id & 3;
  const int tid = threadIdx.x;
  const int w = tid >> 6, l = tid & 63;
  const int lq = l & 15, g = l >> 4;
  const int mb = w*64;

  // ---- phase 1: projection ----
  short8v bx[4][4];
  #pragma unroll
  for(int ms=0; ms<4; ++ms){
    const size_t row = (size_t)i*NNX + mb + ms*16 + lq;
    #pragma unroll
    for(int kc=0; kc<4; ++kc)
      bx[ms][kc] = *(const short8v*)(xln + row*CCX + kc*32 + g*8);
  }
  float4v greg[2][4];
  char* qsb = (char*)Qs;
  char* ksb = (char*)Ks;
  char* vtb = (char*)Vt;
  #pragma unroll
  for(int mat=0; mat<4; ++mat){
    #pragma unroll
    for(int half=0; half<2; ++half){
      const int n0 = mat*128 + h*32 + half*16;
      float4v acc[4];
      #pragma unroll
      for(int ms=0; ms<4; ++ms) acc[ms] = (float4v)(0.f);
      #pragma unroll
      for(int kc=0; kc<4; ++kc){
        short8v aw = *(const short8v*)(wT + (size_t)(n0 + lq)*CCX + kc*32 + g*8);
        #pragma unroll
        for(int ms=0; ms<4; ++ms) acc[ms] = MFMA(aw, bx[ms][kc], acc[ms]);
      }
      if(mat==0){        // Q: scale, to swizzled 64B-pitch LDS
        #pragma unroll
        for(int ms=0; ms<4; ++ms){
          const int row = mb + ms*16 + lq;
          uint2 pw; pw.x = pk2(acc[ms][0]*0.17677669529663687f, acc[ms][1]*0.17677669529663687f);
                    pw.y = pk2(acc[ms][2]*0.17677669529663687f, acc[ms][3]*0.17677669529663687f);
          const int slot = (half*2 + (g>>1)) ^ (row&3);
          *(uint2*)(qsb + (size_t)row*64 + slot*16 + (g&1)*8) = pw;
        }
      } else if(mat==1){ // K: to LDS
        #pragma unroll
        for(int ms=0; ms<4; ++ms){
          const int row = mb + ms*16 + lq;
          uint2 pw; pw.x = pk2(acc[ms][0], acc[ms][1]);
                    pw.y = pk2(acc[ms][2], acc[ms][3]);
          *(uint2*)(ksb + (size_t)row*80 + half*32 + g*8) = pw;
        }
      } else if(mat==2){ // V: permuted+swizzled V^T scatter
        #pragma unroll
        for(int ms=0; ms<4; ++ms){
          const int k = mb + ms*16 + lq;
          const int j = k & 31;
          const int kap = (k & ~31) + 8*((j>>2)&3) + 4*((j>>4)&1) + (j&3);
          #pragma unroll
          for(int r=0; r<4; ++r){
            const int d = half*16 + 4*g + r;
            const int off = d*512 + ((2*kap) ^ ((d&7)<<4));
            *(unsigned short*)(vtb + off) = __bfloat16_as_ushort(__float2bfloat16(acc[ms][r]));
          }
        }
      } else {           // G: + bias, keep in registers (layout matches PV out)
        const float4 bg4 = *(const float4*)(bg + h*32 + half*16 + 4*g);
        #pragma unroll
        for(int ms=0; ms<4; ++ms){
          float4v t = acc[ms];
          t[0]+=bg4.x; t[1]+=bg4.y; t[2]+=bg4.z; t[3]+=bg4.w;
          greg[half][ms] = t;
        }
      }
    }
  }
  __syncthreads();

  // ---- phase 2: attention ----
  bf16* obh = op + ((size_t)h*NIJ + (size_t)i*NNX)*CHDX;
  #pragma unroll 1
  for(int sub=0; sub<4; ++sub){
    const int q0 = mb + sub*16;
    const int q  = q0 + lq;
    short8v qf = *(const short8v*)(qsb + (size_t)q*64 + (((g ^ (q&3)))<<4));
    const float* tbq = tb2 + (size_t)h*NIJ + (size_t)q*NNX;
    float4v s[16];
    #pragma unroll
    for(int t=0;t<16;++t){
      short8v ak = *(const short8v*)(ksb + (size_t)(t*16 + lq)*80 + g*16);
      float4v bb = *(const float4v*)(tbq + t*16 + g*4);
      s[t] = MFMA(ak, qf, bb);
    }
    float m = -1e30f;
    #pragma unroll
    for(int t=0;t<16;++t)
      m = fmaxf(m, fmaxf(fmaxf(s[t][0], s[t][1]), fmaxf(s[t][2], s[t][3])));
    m = fmaxf(m, __shfl_xor(m,16));
    m = fmaxf(m, __shfl_xor(m,32));
    float lsum = 0.f;
    #pragma unroll
    for(int t=0;t<16;++t){
      #pragma unroll
      for(int r=0;r<4;++r){ float e = __expf(s[t][r]-m); s[t][r]=e; lsum+=e; }
    }
    lsum += __shfl_xor(lsum,16);
    lsum += __shfl_xor(lsum,32);
    const float linv = 1.0f/lsum;
    #pragma unroll
    for(int dt=0; dt<2; ++dt){
      float4v acc = (float4v)(0.f);
      #pragma unroll
      for(int c=0;c<8;++c){
        const int vrow = dt*16 + lq;
        short8v av = *(const short8v*)(vtb + (size_t)vrow*512 + ((16*g + 64*c) ^ ((vrow&7)<<4)));
        uint4 pb;
        pb.x = pk2(s[2*c][0],   s[2*c][1]);
        pb.y = pk2(s[2*c][2],   s[2*c][3]);
        pb.z = pk2(s[2*c+1][0], s[2*c+1][1]);
        pb.w = pk2(s[2*c+1][2], s[2*c+1][3]);
        short8v bp;
        bp[0]=(short)(pb.x&0xffff); bp[1]=(short)(pb.x>>16);
        bp[2]=(short)(pb.y&0xffff); bp[3]=(short)(pb.y>>16);
        bp[4]=(short)(pb.z&0xffff); bp[5]=(short)(pb.z>>16);
        bp[6]=(short)(pb.w&0xffff); bp[7]=(short)(pb.w>>16);
        acc = MFMA(av, bp, acc);
      }
      // gate in-register (greg layout matches: lane lq = q-row, reg r = d)
      const float4v gg = greg[dt][sub];
      float o0 = acc[0]*linv / (1.f + __expf(-gg[0]));
      float o1 = acc[1]*linv / (1.f + __expf(-gg[1]));
      float o2 = acc[2]*linv / (1.f + __expf(-gg[2]));
      float o3 = acc[3]*linv / (1.f + __expf(-gg[3]));
      uint2 pw; pw.x = pk2(o0,o1); pw.y = pk2(o2,o3);
      *(uint2*)(ksb + (size_t)(mb + lq*4 + 2*dt + (g>>1))*80 + 64 + (g&1)*8) = pw;
    }
    // coalesced read-back + nontemporal store (16B/lane)
    {
      const int r2 = l >> 2, c2 = l & 3;
      uint4v ow = *(const uint4v*)(ksb + (size_t)(mb + r2*4 + c2)*80 + 64);
      __builtin_nontemporal_store(ow, (uint4v*)(obh + (size_t)(q0 + r2)*CHDX + c2*8));
    }
  }
}

// MFMA o-projection + residual: x += o @ wo + bo. o is head-major [H][NIJ][32].
template<int TRANS>
__global__ __launch_bounds__(256) void k_oprojm(const bf16* __restrict__ ob,
    const bf16* __restrict__ woT, const float* __restrict__ bo, float* __restrict__ x){
  const int tid = threadIdx.x;
  const int w = tid >> 6, l = tid & 63;
  const int lq = l & 15, g = l >> 4;
  const int mbase = blockIdx.x*128 + w*32;
  short8v bx[2][4];
  #pragma unroll
  for(int ms=0; ms<2; ++ms){
    const size_t mrow = mbase + ms*16 + lq;
    #pragma unroll
    for(int kc=0; kc<4; ++kc)
      bx[ms][kc] = *(const short8v*)(ob + ((size_t)kc*NIJ + mrow)*CHDX + g*8);
  }
  #pragma unroll
  for(int nj=0; nj<8; ++nj){
    float4v acc0 = (float4v)(0.f), acc1 = (float4v)(0.f);
    #pragma unroll
    for(int kc=0; kc<4; ++kc){
      short8v aw = *(const short8v*)(woT + (size_t)(nj*16 + lq)*CCX + kc*32 + g*8);
      acc0 = MFMA(aw, bx[0][kc], acc0);
      acc1 = MFMA(aw, bx[1][kc], acc1);
    }
    const int col = nj*16 + 4*g;
    const float4 bo4 = *(const float4*)(bo + col);
    #pragma unroll
    for(int ms=0; ms<2; ++ms){
      const int r = mbase + ms*16 + lq;
      const int ii = r>>8, jj = r&255;
      float* dst = x + (size_t)(TRANS ? (jj*NNX+ii) : r)*CCX + col;
      float4 xv = *(float4*)dst;
      xv.x += ((ms==0)?acc0[0]:acc1[0]) + bo4.x;
      xv.y += ((ms==0)?acc0[1]:acc1[1]) + bo4.y;
      xv.z += ((ms==0)?acc0[2]:acc1[2]) + bo4.z;
      xv.w += ((ms==0)?acc0[3]:acc1[3]) + bo4.w;
      *(float4*)dst = xv;
    }
  }
}

extern "C" void kernel_launch(void* const* d_in, const int* in_sizes, int n_in,
                              void* d_out, int out_size, void* d_ws, size_t ws_size,
                              hipStream_t stream){
  const float* cmap = (const float*)d_in[0];
  char* ws = (char*)d_ws;
  float* x   = (float*)(ws);
  bf16* xln  = (bf16*)(ws + 33554432);
  bf16* ob   = (bf16*)(ws + 50331648);
  float* tb2 = (float*)(ws + 117440512);
  bf16* wT   = (bf16*)d_out;              // 160KB scratch at head of d_out; k_tout overwrites last
  bf16* woT  = wT + 65536;
  float* outp = (float*)d_out;

  for(int p=0;p<2;++p){
    const int b = 1 + 10*p;
    const float* lnw = (const float*)d_in[b+0];
    const float* lnb = (const float*)d_in[b+1];
    const float* wq  = (const float*)d_in[b+2];
    const float* wk  = (const float*)d_in[b+3];
    const float* wv  = (const float*)d_in[b+4];
    const float* wz  = (const float*)d_in[b+5];
    const float* wg  = (const float*)d_in[b+6];
    const float* bg  = (const float*)d_in[b+7];
    const float* wo  = (const float*)d_in[b+8];
    const float* bo  = (const float*)d_in[b+9];

    k_cvtw<<<320, 256, 0, stream>>>(wq, wk, wv, wg, wo, wT);

    if(p==0) k_lntin<<<dim3(8,NNX), dim3(32,8), 0, stream>>>(cmap, lnw, lnb, wz, x, xln, tb2);
    else     k_lntb<1><<<NIJ/4, dim3(64,4), 0, stream>>>(x, lnw, lnb, wz, xln, tb2);

    k_fattn<<<1024, 256, 0, stream>>>(xln, wT, bg, tb2, ob);

    if(p==0) k_oprojm<0><<<NIJ/128, 256, 0, stream>>>(ob, woT, bo, x);
    else     k_oprojm<1><<<NIJ/128, 256, 0, stream>>>(ob, woT, bo, x);
  }

  k_tout<<<dim3(8,4,NNX), dim3(32,8), 0, stream>>>(x, outp);
}

// Round 15
// 235.349 us; speedup vs baseline: 1.0355x; 1.0355x over previous
//
#include <hip/hip_runtime.h>
#include <hip/hip_bf16.h>

#define NNX 256
#define CCX 128
#define HHX 4
#define CHDX 32
#define NIJ (NNX*NNX)

typedef __hip_bfloat16 bf16;
typedef __hip_bfloat162 bf162;
typedef __attribute__((ext_vector_type(8))) short short8v;
typedef __attribute__((ext_vector_type(4))) float float4v;
typedef __attribute__((ext_vector_type(4))) unsigned int uint4v;

__device__ __forceinline__ float4v MFMA(short8v a, short8v b, float4v c){
  return __builtin_amdgcn_mfma_f32_16x16x32_bf16(a, b, c, 0, 0, 0);
}

__device__ __forceinline__ unsigned pk2(float a, float b){
  unsigned short ua = __bfloat16_as_ushort(__float2bfloat16(a));
  unsigned short ub = __bfloat16_as_ushort(__float2bfloat16(b));
  return (unsigned)ua | ((unsigned)ub << 16);
}
__device__ __forceinline__ float ubf(unsigned short u){
  return __bfloat162float(__ushort_as_bfloat16(u));
}

// x [I,J,C] -> out [C,I,J]
__global__ __launch_bounds__(256) void k_tout(const float* __restrict__ x, float* __restrict__ out){
  __shared__ float t[32][33];
  const int i = blockIdx.z, jt = blockIdx.x, ct = blockIdx.y;
  const int tx = threadIdx.x, ty = threadIdx.y;
  #pragma unroll
  for(int k=0;k<32;k+=8){
    t[ty+k][tx] = x[((size_t)i*NNX + jt*32+ty+k)*CCX + ct*32 + tx];
  }
  __syncthreads();
  #pragma unroll
  for(int k=0;k<32;k+=8){
    out[(size_t)(ct*32+ty+k)*NIJ + (size_t)i*NNX + jt*32 + tx] = t[tx][ty+k];
  }
}

// FUSED pass-1 front-end: cmap [C,I,J] tile-transpose + LayerNorm + tb.
// x gets the RAW transposed cmap (residual base); xln/tb2 get the LN outputs.
__global__ __launch_bounds__(256) void k_lntin(const float* __restrict__ cmap,
    const float* __restrict__ w, const float* __restrict__ b,
    const float* __restrict__ wz, float* __restrict__ x,
    bf16* __restrict__ xln, float* __restrict__ tb2){
  __shared__ float t[32][130];
  const int jt = blockIdx.x, i = blockIdx.y;
  const int tx = threadIdx.x, ty = threadIdx.y;   // 32, 8
  #pragma unroll
  for(int kk=0; kk<16; ++kk){
    const int c = kk*8 + ty;
    t[tx][c] = cmap[(size_t)c*NIJ + (size_t)i*NNX + jt*32 + tx];
  }
  __syncthreads();
  const int tid = ty*32 + tx;
  const int row = tid >> 3, cs = tid & 7;        // 32 rows x 8 c-slots
  const int c0 = cs*16;
  float v[16];
  #pragma unroll
  for(int u=0;u<16;++u) v[u] = t[row][c0+u];
  float s=0.f, s2=0.f;
  #pragma unroll
  for(int u=0;u<16;++u){ s += v[u]; s2 += v[u]*v[u]; }
  #pragma unroll
  for(int off=4; off>0; off>>=1){ s += __shfl_xor(s,off); s2 += __shfl_xor(s2,off); }
  const float mu = s*0.0078125f;
  const float var = s2*0.0078125f - mu*mu;
  const float rs = rsqrtf(var+1e-5f);
  const int r = i*NNX + jt*32 + row;
  float a[16];
  #pragma unroll
  for(int u=0;u<16;++u) a[u] = (v[u]-mu)*rs*w[c0+u]+b[c0+u];
  // x = RAW transposed cmap (residual base)
  float* xd = x + (size_t)r*CCX + c0;
  #pragma unroll
  for(int u4=0;u4<4;++u4){
    float4 f4; f4.x=v[u4*4]; f4.y=v[u4*4+1]; f4.z=v[u4*4+2]; f4.w=v[u4*4+3];
    *(float4*)(xd + u4*4) = f4;
  }
  // xln (bf16) = LN output
  bf16* xl = xln + (size_t)r*CCX + c0;
  #pragma unroll
  for(int u8=0;u8<4;++u8){
    uint2 pw; pw.x = pk2(a[u8*4], a[u8*4+1]); pw.y = pk2(a[u8*4+2], a[u8*4+3]);
    *(uint2*)(xl + u8*4) = pw;
  }
  // tb = x_ln @ wz
  float acc[4] = {0.f,0.f,0.f,0.f};
  #pragma unroll
  for(int u=0;u<16;++u){
    #pragma unroll
    for(int hh=0;hh<4;++hh) acc[hh] += a[u]*wz[(c0+u)*4+hh];
  }
  #pragma unroll
  for(int off=4; off>0; off>>=1){
    #pragma unroll
    for(int hh=0;hh<4;++hh) acc[hh] += __shfl_xor(acc[hh], off);
  }
  if(cs==0){
    #pragma unroll
    for(int hh=0;hh<4;++hh) tb2[(size_t)hh*NIJ + r] = acc[hh];
  }
}

// fused LayerNorm + triangle-bias projection for pass 2 (reads x transposed).
template<int TRANS>
__global__ __launch_bounds__(256) void k_lntb(const float* __restrict__ x,
    const float* __restrict__ w, const float* __restrict__ b,
    const float* __restrict__ wz, bf16* __restrict__ xln, float* __restrict__ tb2){
  const int r = blockIdx.x*4 + threadIdx.y;
  const int ii = r>>8, jj = r&255;
  const float* src = x + (size_t)(TRANS ? (jj*NNX+ii) : r)*CCX;
  const int c = threadIdx.x*2;
  float2 v = *(const float2*)(src+c);
  float s = v.x+v.y, s2 = v.x*v.x+v.y*v.y;
  #pragma unroll
  for(int off=32; off>0; off>>=1){ s += __shfl_xor(s,off); s2 += __shfl_xor(s2,off); }
  float mu = s*0.0078125f;
  float var = s2*0.0078125f - mu*mu;
  float rs = rsqrtf(var+1e-5f);
  float a0 = (v.x-mu)*rs*w[c]+b[c];
  float a1 = (v.y-mu)*rs*w[c+1]+b[c+1];
  bf162 hp; hp.x = __float2bfloat16(a0); hp.y = __float2bfloat16(a1);
  *(bf162*)(xln + (size_t)r*CCX + c) = hp;
  float acc[4];
  #pragma unroll
  for(int hh=0;hh<4;++hh) acc[hh] = a0*wz[c*4+hh] + a1*wz[(c+1)*4+hh];
  #pragma unroll
  for(int off=32; off>0; off>>=1){
    #pragma unroll
    for(int hh=0;hh<4;++hh) acc[hh] += __shfl_xor(acc[hh], off);
  }
  if(threadIdx.x==0){
    #pragma unroll
    for(int hh=0;hh<4;++hh) tb2[(size_t)hh*NIJ + r] = acc[hh];
  }
}

// convert+transpose weights: wT[0,512): {wq,wk,wv,wg}^T ; +65536: woT
__global__ __launch_bounds__(256) void k_cvtw(const float* __restrict__ wq,
    const float* __restrict__ wk, const float* __restrict__ wv,
    const float* __restrict__ wg, const float* __restrict__ wo, bf16* __restrict__ wT){
  int idx = blockIdx.x*256 + threadIdx.x;   // 81920
  if(idx < 65536){
    int n = idx >> 7, k = idx & 127;
    const float* W = (n<128)?wq:(n<256)?wk:(n<384)?wv:wg;
    wT[idx] = __float2bfloat16(W[k*CCX + (n&127)]);
  } else {
    int idx2 = idx - 65536;
    int n = idx2 >> 7, k = idx2 & 127;
    wT[idx] = __float2bfloat16(wo[k*CCX + n]);
  }
}

// one q-subtile. tbc = this sub's prefetched bias frags; tbn = next sub's
// (loads issued FIRST so global latency hides under this sub's compute).
template<int SUB, bool PRE>
__device__ __forceinline__ void attn_sub(const int mb,
    const int lq, const int g, const int l,
    float4v (&tbc)[16], float4v (&tbn)[16],
    const float4v gg0, const float4v gg1,
    const char* qsb, char* ksb, const char* vtb,
    const float* tbq_base, bf16* __restrict__ obh){
  const int q0 = mb + SUB*16;
  const int q  = q0 + lq;
  if(PRE){
    const float* tn = tbq_base + (size_t)(mb + (SUB+1)*16 + lq)*NNX;
    #pragma unroll
    for(int t=0;t<16;++t) tbn[t] = *(const float4v*)(tn + t*16 + g*4);
  }
  short8v qf = *(const short8v*)(qsb + (size_t)q*80 + g*16);
  float4v s[16];
  #pragma unroll
  for(int t=0;t<16;++t){
    short8v ak = *(const short8v*)(ksb + (size_t)(t*16 + lq)*80 + g*16);
    s[t] = MFMA(ak, qf, tbc[t]);
  }
  float m = -1e30f;
  #pragma unroll
  for(int t=0;t<16;++t)
    m = fmaxf(m, fmaxf(fmaxf(s[t][0], s[t][1]), fmaxf(s[t][2], s[t][3])));
  m = fmaxf(m, __shfl_xor(m,16));
  m = fmaxf(m, __shfl_xor(m,32));
  float lsum = 0.f;
  #pragma unroll
  for(int t=0;t<16;++t){
    #pragma unroll
    for(int r=0;r<4;++r){ float e = __expf(s[t][r]-m); s[t][r]=e; lsum+=e; }
  }
  lsum += __shfl_xor(lsum,16);
  lsum += __shfl_xor(lsum,32);
  const float linv = 1.0f/lsum;
  #pragma unroll
  for(int dt=0; dt<2; ++dt){
    float4v acc = (float4v)(0.f);
    #pragma unroll
    for(int c=0;c<8;++c){
      const int vrow = dt*16 + lq;
      short8v av = *(const short8v*)(vtb + (size_t)vrow*512 + ((16*g + 64*c) ^ ((vrow&7)<<4)));
      uint4 pb;
      pb.x = pk2(s[2*c][0],   s[2*c][1]);
      pb.y = pk2(s[2*c][2],   s[2*c][3]);
      pb.z = pk2(s[2*c+1][0], s[2*c+1][1]);
      pb.w = pk2(s[2*c+1][2], s[2*c+1][3]);
      short8v bp;
      bp[0]=(short)(pb.x&0xffff); bp[1]=(short)(pb.x>>16);
      bp[2]=(short)(pb.y&0xffff); bp[3]=(short)(pb.y>>16);
      bp[4]=(short)(pb.z&0xffff); bp[5]=(short)(pb.z>>16);
      bp[6]=(short)(pb.w&0xffff); bp[7]=(short)(pb.w>>16);
      acc = MFMA(av, bp, acc);
    }
    const float4v gg = dt ? gg1 : gg0;
    float o0 = acc[0]*linv / (1.f + __expf(-gg[0]));
    float o1 = acc[1]*linv / (1.f + __expf(-gg[1]));
    float o2 = acc[2]*linv / (1.f + __expf(-gg[2]));
    float o3 = acc[3]*linv / (1.f + __expf(-gg[3]));
    uint2 pw; pw.x = pk2(o0,o1); pw.y = pk2(o2,o3);
    *(uint2*)(ksb + (size_t)(mb + lq*4 + 2*dt + (g>>1))*80 + 64 + (g&1)*8) = pw;
  }
  {
    const int r2 = l >> 2, c2 = l & 3;
    uint4v ow = *(const uint4v*)(ksb + (size_t)(mb + r2*4 + c2)*80 + 64);
    __builtin_nontemporal_store(ow, (uint4v*)(obh + (size_t)(q0 + r2)*CHDX + c2*8));
  }
}

// FUSED projection + attention per (i,h) — r13 structure (68us) + tb2
// register double-buffer prefetch (T14): sub N+1's 16 bias loads issue at the
// top of sub N; sub 0's issue before __syncthreads (overlap projection tail).
// VGPR headroom is free at 2 blocks/CU (LDS-capped) -> prefetch costs nothing.
__global__ __launch_bounds__(256,2) void k_fattn(const bf16* __restrict__ xln,
    const bf16* __restrict__ wT, const float* __restrict__ bg,
    const float* __restrict__ tb2, bf16* __restrict__ op){
  __shared__ unsigned short Qs[256*40];      // 20KB  Q rows [q][d], 80B pitch
  __shared__ unsigned short Ks[256*40];      // 20KB  K rows [k][d] + O-bounce holes
  __shared__ unsigned short Vt[32*256];      // 16KB  V^T [d][kappa], XOR-swizzled
  const int id = blockIdx.x;
  const int i = id >> 2, h = id & 3;
  const int tid = threadIdx.x;
  const int w = tid >> 6, l = tid & 63;
  const int lq = l & 15, g = l >> 4;
  const int mb = w*64;

  // ---- phase 1: projection ----
  short8v bx[4][4];
  #pragma unroll
  for(int ms=0; ms<4; ++ms){
    const size_t row = (size_t)i*NNX + mb + ms*16 + lq;
    #pragma unroll
    for(int kc=0; kc<4; ++kc)
      bx[ms][kc] = *(const short8v*)(xln + row*CCX + kc*32 + g*8);
  }
  float4v greg[2][4];
  char* qsb = (char*)Qs;
  char* ksb = (char*)Ks;
  char* vtb = (char*)Vt;
  #pragma unroll
  for(int mat=0; mat<4; ++mat){
    #pragma unroll
    for(int half=0; half<2; ++half){
      const int n0 = mat*128 + h*32 + half*16;
      float4v acc[4];
      #pragma unroll
      for(int ms=0; ms<4; ++ms) acc[ms] = (float4v)(0.f);
      #pragma unroll
      for(int kc=0; kc<4; ++kc){
        short8v aw = *(const short8v*)(wT + (size_t)(n0 + lq)*CCX + kc*32 + g*8);
        #pragma unroll
        for(int ms=0; ms<4; ++ms) acc[ms] = MFMA(aw, bx[ms][kc], acc[ms]);
      }
      if(mat==0){        // Q: scale, to LDS
        #pragma unroll
        for(int ms=0; ms<4; ++ms){
          const int row = mb + ms*16 + lq;
          uint2 pw; pw.x = pk2(acc[ms][0]*0.17677669529663687f, acc[ms][1]*0.17677669529663687f);
                    pw.y = pk2(acc[ms][2]*0.17677669529663687f, acc[ms][3]*0.17677669529663687f);
          *(uint2*)(qsb + (size_t)row*80 + half*32 + g*8) = pw;
        }
      } else if(mat==1){ // K: to LDS
        #pragma unroll
        for(int ms=0; ms<4; ++ms){
          const int row = mb + ms*16 + lq;
          uint2 pw; pw.x = pk2(acc[ms][0], acc[ms][1]);
                    pw.y = pk2(acc[ms][2], acc[ms][3]);
          *(uint2*)(ksb + (size_t)row*80 + half*32 + g*8) = pw;
        }
      } else if(mat==2){ // V: permuted+swizzled V^T scatter
        #pragma unroll
        for(int ms=0; ms<4; ++ms){
          const int k = mb + ms*16 + lq;
          const int j = k & 31;
          const int kap = (k & ~31) + 8*((j>>2)&3) + 4*((j>>4)&1) + (j&3);
          #pragma unroll
          for(int r=0; r<4; ++r){
            const int d = half*16 + 4*g + r;
            const int off = d*512 + ((2*kap) ^ ((d&7)<<4));
            *(unsigned short*)(vtb + off) = __bfloat16_as_ushort(__float2bfloat16(acc[ms][r]));
          }
        }
      } else {           // G: + bias, keep in registers (layout matches PV out)
        const float4 bg4 = *(const float4*)(bg + h*32 + half*16 + 4*g);
        #pragma unroll
        for(int ms=0; ms<4; ++ms){
          float4v t = acc[ms];
          t[0]+=bg4.x; t[1]+=bg4.y; t[2]+=bg4.z; t[3]+=bg4.w;
          greg[half][ms] = t;
        }
      }
    }
  }

  // prefetch sub0's bias frags before the barrier (overlaps projection drain)
  const float* tbq_base = tb2 + (size_t)h*NIJ;
  float4v tbA[16], tbB[16];
  {
    const float* t0 = tbq_base + (size_t)(mb + lq)*NNX;
    #pragma unroll
    for(int t=0;t<16;++t) tbA[t] = *(const float4v*)(t0 + t*16 + g*4);
  }
  __syncthreads();

  // ---- phase 2: attention, 4 static q-subtiles, tb double-buffered ----
  bf16* obh = op + ((size_t)h*NIJ + (size_t)i*NNX)*CHDX;
  attn_sub<0,true >(mb, lq, g, l, tbA, tbB, greg[0][0], greg[1][0], qsb, ksb, vtb, tbq_base, obh);
  attn_sub<1,true >(mb, lq, g, l, tbB, tbA, greg[0][1], greg[1][1], qsb, ksb, vtb, tbq_base, obh);
  attn_sub<2,true >(mb, lq, g, l, tbA, tbB, greg[0][2], greg[1][2], qsb, ksb, vtb, tbq_base, obh);
  attn_sub<3,false>(mb, lq, g, l, tbB, tbA, greg[0][3], greg[1][3], qsb, ksb, vtb, tbq_base, obh);
}

// MFMA o-projection + residual: x += o @ wo + bo. o is head-major [H][NIJ][32].
template<int TRANS>
__global__ __launch_bounds__(256) void k_oprojm(const bf16* __restrict__ ob,
    const bf16* __restrict__ woT, const float* __restrict__ bo, float* __restrict__ x){
  const int tid = threadIdx.x;
  const int w = tid >> 6, l = tid & 63;
  const int lq = l & 15, g = l >> 4;
  const int mbase = blockIdx.x*128 + w*32;
  short8v bx[2][4];
  #pragma unroll
  for(int ms=0; ms<2; ++ms){
    const size_t mrow = mbase + ms*16 + lq;
    #pragma unroll
    for(int kc=0; kc<4; ++kc)
      bx[ms][kc] = *(const short8v*)(ob + ((size_t)kc*NIJ + mrow)*CHDX + g*8);
  }
  #pragma unroll
  for(int nj=0; nj<8; ++nj){
    float4v acc0 = (float4v)(0.f), acc1 = (float4v)(0.f);
    #pragma unroll
    for(int kc=0; kc<4; ++kc){
      short8v aw = *(const short8v*)(woT + (size_t)(nj*16 + lq)*CCX + kc*32 + g*8);
      acc0 = MFMA(aw, bx[0][kc], acc0);
      acc1 = MFMA(aw, bx[1][kc], acc1);
    }
    const int col = nj*16 + 4*g;
    const float4 bo4 = *(const float4*)(bo + col);
    #pragma unroll
    for(int ms=0; ms<2; ++ms){
      const int r = mbase + ms*16 + lq;
      const int ii = r>>8, jj = r&255;
      float* dst = x + (size_t)(TRANS ? (jj*NNX+ii) : r)*CCX + col;
      float4 xv = *(float4*)dst;
      xv.x += ((ms==0)?acc0[0]:acc1[0]) + bo4.x;
      xv.y += ((ms==0)?acc0[1]:acc1[1]) + bo4.y;
      xv.z += ((ms==0)?acc0[2]:acc1[2]) + bo4.z;
      xv.w += ((ms==0)?acc0[3]:acc1[3]) + bo4.w;
      *(float4*)dst = xv;
    }
  }
}

extern "C" void kernel_launch(void* const* d_in, const int* in_sizes, int n_in,
                              void* d_out, int out_size, void* d_ws, size_t ws_size,
                              hipStream_t stream){
  const float* cmap = (const float*)d_in[0];
  char* ws = (char*)d_ws;
  float* x   = (float*)(ws);
  bf16* xln  = (bf16*)(ws + 33554432);
  bf16* ob   = (bf16*)(ws + 50331648);
  float* tb2 = (float*)(ws + 117440512);
  bf16* wT   = (bf16*)d_out;              // 160KB scratch at head of d_out; k_tout overwrites last
  bf16* woT  = wT + 65536;
  float* outp = (float*)d_out;

  for(int p=0;p<2;++p){
    const int b = 1 + 10*p;
    const float* lnw = (const float*)d_in[b+0];
    const float* lnb = (const float*)d_in[b+1];
    const float* wq  = (const float*)d_in[b+2];
    const float* wk  = (const float*)d_in[b+3];
    const float* wv  = (const float*)d_in[b+4];
    const float* wz  = (const float*)d_in[b+5];
    const float* wg  = (const float*)d_in[b+6];
    const float* bg  = (const float*)d_in[b+7];
    const float* wo  = (const float*)d_in[b+8];
    const float* bo  = (const float*)d_in[b+9];

    k_cvtw<<<320, 256, 0, stream>>>(wq, wk, wv, wg, wo, wT);

    if(p==0) k_lntin<<<dim3(8,NNX), dim3(32,8), 0, stream>>>(cmap, lnw, lnb, wz, x, xln, tb2);
    else     k_lntb<1><<<NIJ/4, dim3(64,4), 0, stream>>>(x, lnw, lnb, wz, xln, tb2);

    k_fattn<<<1024, 256, 0, stream>>>(xln, wT, bg, tb2, ob);

    if(p==0) k_oprojm<0><<<NIJ/128, 256, 0, stream>>>(ob, woT, bo, x);
    else     k_oprojm<1><<<NIJ/128, 256, 0, stream>>>(ob, woT, bo, x);
  }

  k_tout<<<dim3(8,4,NNX), dim3(32,8), 0, stream>>>(x, outp);
}

// Round 16
// 234.761 us; speedup vs baseline: 1.0381x; 1.0025x over previous
//
#include <hip/hip_runtime.h>
#include <hip/hip_bf16.h>

#define NNX 256
#define CCX 128
#define HHX 4
#define CHDX 32
#define NIJ (NNX*NNX)

typedef __hip_bfloat16 bf16;
typedef __hip_bfloat162 bf162;
typedef __attribute__((ext_vector_type(8))) short short8v;
typedef __attribute__((ext_vector_type(4))) float float4v;
typedef __attribute__((ext_vector_type(4))) unsigned int uint4v;

__device__ __forceinline__ float4v MFMA(short8v a, short8v b, float4v c){
  return __builtin_amdgcn_mfma_f32_16x16x32_bf16(a, b, c, 0, 0, 0);
}

__device__ __forceinline__ unsigned pk2(float a, float b){
  unsigned short ua = __bfloat16_as_ushort(__float2bfloat16(a));
  unsigned short ub = __bfloat16_as_ushort(__float2bfloat16(b));
  return (unsigned)ua | ((unsigned)ub << 16);
}
__device__ __forceinline__ float ubf(unsigned short u){
  return __bfloat162float(__ushort_as_bfloat16(u));
}

// x [I,J,C] -> out [C,I,J]
__global__ __launch_bounds__(256) void k_tout(const float* __restrict__ x, float* __restrict__ out){
  __shared__ float t[32][33];
  const int i = blockIdx.z, jt = blockIdx.x, ct = blockIdx.y;
  const int tx = threadIdx.x, ty = threadIdx.y;
  #pragma unroll
  for(int k=0;k<32;k+=8){
    t[ty+k][tx] = x[((size_t)i*NNX + jt*32+ty+k)*CCX + ct*32 + tx];
  }
  __syncthreads();
  #pragma unroll
  for(int k=0;k<32;k+=8){
    out[(size_t)(ct*32+ty+k)*NIJ + (size_t)i*NNX + jt*32 + tx] = t[tx][ty+k];
  }
}

// FUSED pass-1 front-end: cmap [C,I,J] tile-transpose + LayerNorm + tb.
// x gets the RAW transposed cmap (residual base); xln/tb2 get the LN outputs.
__global__ __launch_bounds__(256) void k_lntin(const float* __restrict__ cmap,
    const float* __restrict__ w, const float* __restrict__ b,
    const float* __restrict__ wz, float* __restrict__ x,
    bf16* __restrict__ xln, float* __restrict__ tb2){
  __shared__ float t[32][130];
  const int jt = blockIdx.x, i = blockIdx.y;
  const int tx = threadIdx.x, ty = threadIdx.y;   // 32, 8
  #pragma unroll
  for(int kk=0; kk<16; ++kk){
    const int c = kk*8 + ty;
    t[tx][c] = cmap[(size_t)c*NIJ + (size_t)i*NNX + jt*32 + tx];
  }
  __syncthreads();
  const int tid = ty*32 + tx;
  const int row = tid >> 3, cs = tid & 7;        // 32 rows x 8 c-slots
  const int c0 = cs*16;
  float v[16];
  #pragma unroll
  for(int u=0;u<16;++u) v[u] = t[row][c0+u];
  float s=0.f, s2=0.f;
  #pragma unroll
  for(int u=0;u<16;++u){ s += v[u]; s2 += v[u]*v[u]; }
  #pragma unroll
  for(int off=4; off>0; off>>=1){ s += __shfl_xor(s,off); s2 += __shfl_xor(s2,off); }
  const float mu = s*0.0078125f;
  const float var = s2*0.0078125f - mu*mu;
  const float rs = rsqrtf(var+1e-5f);
  const int r = i*NNX + jt*32 + row;
  float a[16];
  #pragma unroll
  for(int u=0;u<16;++u) a[u] = (v[u]-mu)*rs*w[c0+u]+b[c0+u];
  // x = RAW transposed cmap (residual base)
  float* xd = x + (size_t)r*CCX + c0;
  #pragma unroll
  for(int u4=0;u4<4;++u4){
    float4 f4; f4.x=v[u4*4]; f4.y=v[u4*4+1]; f4.z=v[u4*4+2]; f4.w=v[u4*4+3];
    *(float4*)(xd + u4*4) = f4;
  }
  // xln (bf16) = LN output
  bf16* xl = xln + (size_t)r*CCX + c0;
  #pragma unroll
  for(int u8=0;u8<4;++u8){
    uint2 pw; pw.x = pk2(a[u8*4], a[u8*4+1]); pw.y = pk2(a[u8*4+2], a[u8*4+3]);
    *(uint2*)(xl + u8*4) = pw;
  }
  // tb = x_ln @ wz
  float acc[4] = {0.f,0.f,0.f,0.f};
  #pragma unroll
  for(int u=0;u<16;++u){
    #pragma unroll
    for(int hh=0;hh<4;++hh) acc[hh] += a[u]*wz[(c0+u)*4+hh];
  }
  #pragma unroll
  for(int off=4; off>0; off>>=1){
    #pragma unroll
    for(int hh=0;hh<4;++hh) acc[hh] += __shfl_xor(acc[hh], off);
  }
  if(cs==0){
    #pragma unroll
    for(int hh=0;hh<4;++hh) tb2[(size_t)hh*NIJ + r] = acc[hh];
  }
}

// fused LayerNorm + triangle-bias projection for pass 2 (reads x transposed).
template<int TRANS>
__global__ __launch_bounds__(256) void k_lntb(const float* __restrict__ x,
    const float* __restrict__ w, const float* __restrict__ b,
    const float* __restrict__ wz, bf16* __restrict__ xln, float* __restrict__ tb2){
  const int r = blockIdx.x*4 + threadIdx.y;
  const int ii = r>>8, jj = r&255;
  const float* src = x + (size_t)(TRANS ? (jj*NNX+ii) : r)*CCX;
  const int c = threadIdx.x*2;
  float2 v = *(const float2*)(src+c);
  float s = v.x+v.y, s2 = v.x*v.x+v.y*v.y;
  #pragma unroll
  for(int off=32; off>0; off>>=1){ s += __shfl_xor(s,off); s2 += __shfl_xor(s2,off); }
  float mu = s*0.0078125f;
  float var = s2*0.0078125f - mu*mu;
  float rs = rsqrtf(var+1e-5f);
  float a0 = (v.x-mu)*rs*w[c]+b[c];
  float a1 = (v.y-mu)*rs*w[c+1]+b[c+1];
  bf162 hp; hp.x = __float2bfloat16(a0); hp.y = __float2bfloat16(a1);
  *(bf162*)(xln + (size_t)r*CCX + c) = hp;
  float acc[4];
  #pragma unroll
  for(int hh=0;hh<4;++hh) acc[hh] = a0*wz[c*4+hh] + a1*wz[(c+1)*4+hh];
  #pragma unroll
  for(int off=32; off>0; off>>=1){
    #pragma unroll
    for(int hh=0;hh<4;++hh) acc[hh] += __shfl_xor(acc[hh], off);
  }
  if(threadIdx.x==0){
    #pragma unroll
    for(int hh=0;hh<4;++hh) tb2[(size_t)hh*NIJ + r] = acc[hh];
  }
}

// convert+transpose weights: wT[0,512): {wq,wk,wv,wg}^T ; +65536: woT
__global__ __launch_bounds__(256) void k_cvtw(const float* __restrict__ wq,
    const float* __restrict__ wk, const float* __restrict__ wv,
    const float* __restrict__ wg, const float* __restrict__ wo, bf16* __restrict__ wT){
  int idx = blockIdx.x*256 + threadIdx.x;   // 81920
  if(idx < 65536){
    int n = idx >> 7, k = idx & 127;
    const float* W = (n<128)?wq:(n<256)?wk:(n<384)?wv:wg;
    wT[idx] = __float2bfloat16(W[k*CCX + (n&127)]);
  } else {
    int idx2 = idx - 65536;
    int n = idx2 >> 7, k = idx2 & 127;
    wT[idx] = __float2bfloat16(wo[k*CCX + n]);
  }
}

// one q-subtile (static SUB: all reg arrays static-indexed)
template<int SUB>
__device__ __forceinline__ void attn_sub(const int mb,
    const int lq, const int g, const int l,
    short8v qf, uint2 pgl, uint2 pgh,
    char* ksb, const char* vtb,
    const float* tbq_base, bf16* __restrict__ obh){
  const int q0 = mb + SUB*16;
  const float* tbq = tbq_base + (size_t)(q0 + lq)*NNX;
  float4v s[16];
  #pragma unroll
  for(int t=0;t<16;++t){
    short8v ak = *(const short8v*)(ksb + (size_t)(t*16 + lq)*80 + g*16);
    float4v bb = *(const float4v*)(tbq + t*16 + g*4);
    s[t] = MFMA(ak, qf, bb);
  }
  float m = -1e30f;
  #pragma unroll
  for(int t=0;t<16;++t)
    m = fmaxf(m, fmaxf(fmaxf(s[t][0], s[t][1]), fmaxf(s[t][2], s[t][3])));
  m = fmaxf(m, __shfl_xor(m,16));
  m = fmaxf(m, __shfl_xor(m,32));
  float lsum = 0.f;
  #pragma unroll
  for(int t=0;t<16;++t){
    #pragma unroll
    for(int r=0;r<4;++r){ float e = __expf(s[t][r]-m); s[t][r]=e; lsum+=e; }
  }
  lsum += __shfl_xor(lsum,16);
  lsum += __shfl_xor(lsum,32);
  const float linv = 1.0f/lsum;
  #pragma unroll
  for(int dt=0; dt<2; ++dt){
    float4v acc = (float4v)(0.f);
    #pragma unroll
    for(int c=0;c<8;++c){
      const int vrow = dt*16 + lq;
      short8v av = *(const short8v*)(vtb + (size_t)vrow*512 + ((16*g + 64*c) ^ ((vrow&7)<<4)));
      uint4 pb;
      pb.x = pk2(s[2*c][0],   s[2*c][1]);
      pb.y = pk2(s[2*c][2],   s[2*c][3]);
      pb.z = pk2(s[2*c+1][0], s[2*c+1][1]);
      pb.w = pk2(s[2*c+1][2], s[2*c+1][3]);
      short8v bp;
      bp[0]=(short)(pb.x&0xffff); bp[1]=(short)(pb.x>>16);
      bp[2]=(short)(pb.y&0xffff); bp[3]=(short)(pb.y>>16);
      bp[4]=(short)(pb.z&0xffff); bp[5]=(short)(pb.z>>16);
      bp[6]=(short)(pb.w&0xffff); bp[7]=(short)(pb.w>>16);
      acc = MFMA(av, bp, acc);
    }
    const uint2 pg = dt ? pgh : pgl;
    float g0 = ubf((unsigned short)(pg.x & 0xffff));
    float g1 = ubf((unsigned short)(pg.x >> 16));
    float g2 = ubf((unsigned short)(pg.y & 0xffff));
    float g3 = ubf((unsigned short)(pg.y >> 16));
    float o0 = acc[0]*linv / (1.f + __expf(-g0));
    float o1 = acc[1]*linv / (1.f + __expf(-g1));
    float o2 = acc[2]*linv / (1.f + __expf(-g2));
    float o3 = acc[3]*linv / (1.f + __expf(-g3));
    uint2 pw; pw.x = pk2(o0,o1); pw.y = pk2(o2,o3);
    *(uint2*)(ksb + (size_t)(mb + lq*4 + 2*dt + (g>>1))*80 + 64 + (g&1)*8) = pw;
  }
  {
    const int r2 = l >> 2, c2 = l & 3;
    uint4v ow = *(const uint4v*)(ksb + (size_t)(mb + r2*4 + c2)*80 + 64);
    __builtin_nontemporal_store(ow, (uint4v*)(obh + (size_t)(q0 + r2)*CHDX + c2*8));
  }
}

// FUSED projection + attention per (i,h).
// A/B vs r13: ONLY change is Q moves from LDS (20KB) to registers via
// shuffle-transpose (r9/r11-verified mechanism). LDS 56->36KB => 4 blocks/CU.
// Allocator unconstrained ((256,2)); r11 measured VGPR 116, no spill.
// Grid: i = id>>2, h = id&3 (i-major, known-good from r8/r13).
__global__ __launch_bounds__(256,2) void k_fattn(const bf16* __restrict__ xln,
    const bf16* __restrict__ wT, const float* __restrict__ bg,
    const float* __restrict__ tb2, bf16* __restrict__ op){
  __shared__ unsigned short Ks[256*40];      // 20KB  K rows [k][d] + O-bounce holes
  __shared__ unsigned short Vt[32*256];      // 16KB  V^T [d][kappa], XOR-swizzled
  const int id = blockIdx.x;
  const int i = id >> 2, h = id & 3;
  const int tid = threadIdx.x;
  const int w = tid >> 6, l = tid & 63;
  const int lq = l & 15, g = l >> 4;
  const int mb = w*64;

  char* ksb = (char*)Ks;
  char* vtb = (char*)Vt;

  // ---- phase 1: projection ----
  short8v bx[4][4];
  #pragma unroll
  for(int ms=0; ms<4; ++ms){
    const size_t row = (size_t)i*NNX + mb + ms*16 + lq;
    #pragma unroll
    for(int kc=0; kc<4; ++kc)
      bx[ms][kc] = *(const short8v*)(xln + row*CCX + kc*32 + g*8);
  }
  uint4v qfr[4];        // per-sub Q B-frags (bf16x8)
  uint2 pgl[4], pgh[4]; // packed G (+bias) per sub, low/high d-halves

  // Q: compute, pack, in-register shuffle-transpose to B-frag layout
  {
    uint2 pqa0[4], pqa1[4];
    #pragma unroll
    for(int half=0; half<2; ++half){
      const int n0 = h*32 + half*16;
      float4v acc[4];
      #pragma unroll
      for(int ms=0; ms<4; ++ms) acc[ms] = (float4v)(0.f);
      #pragma unroll
      for(int kc=0; kc<4; ++kc){
        short8v aw = *(const short8v*)(wT + (size_t)(n0 + lq)*CCX + kc*32 + g*8);
        #pragma unroll
        for(int ms=0; ms<4; ++ms) acc[ms] = MFMA(aw, bx[ms][kc], acc[ms]);
      }
      #pragma unroll
      for(int ms=0; ms<4; ++ms){
        uint2 pw;
        pw.x = pk2(acc[ms][0]*0.17677669529663687f, acc[ms][1]*0.17677669529663687f);
        pw.y = pk2(acc[ms][2]*0.17677669529663687f, acc[ms][3]*0.17677669529663687f);
        if(half==0) pqa0[ms] = pw; else pqa1[ms] = pw;
      }
    }
    // lane (lq,g) needs Q[row=lq][8g..8g+7]: lanes lq+32(g&1) and +16, half=g>>1
    const int srcA = lq + 32*(g&1);
    const int hsel = g >> 1;
    #pragma unroll
    for(int ms=0; ms<4; ++ms){
      unsigned sx = hsel ? pqa1[ms].x : pqa0[ms].x;
      unsigned sy = hsel ? pqa1[ms].y : pqa0[ms].y;
      qfr[ms].x = __shfl(sx, srcA);
      qfr[ms].y = __shfl(sy, srcA);
      qfr[ms].z = __shfl(sx, srcA+16);
      qfr[ms].w = __shfl(sy, srcA+16);
    }
  }
  // K -> LDS (80B pitch)
  #pragma unroll
  for(int half=0; half<2; ++half){
    const int n0 = 128 + h*32 + half*16;
    float4v acc[4];
    #pragma unroll
    for(int ms=0; ms<4; ++ms) acc[ms] = (float4v)(0.f);
    #pragma unroll
    for(int kc=0; kc<4; ++kc){
      short8v aw = *(const short8v*)(wT + (size_t)(n0 + lq)*CCX + kc*32 + g*8);
      #pragma unroll
      for(int ms=0; ms<4; ++ms) acc[ms] = MFMA(aw, bx[ms][kc], acc[ms]);
    }
    #pragma unroll
    for(int ms=0; ms<4; ++ms){
      const int row = mb + ms*16 + lq;
      uint2 pw; pw.x = pk2(acc[ms][0], acc[ms][1]);
                pw.y = pk2(acc[ms][2], acc[ms][3]);
      *(uint2*)(ksb + (size_t)row*80 + half*32 + g*8) = pw;
    }
  }
  // V -> permuted+swizzled V^T
  #pragma unroll
  for(int half=0; half<2; ++half){
    const int n0 = 256 + h*32 + half*16;
    float4v acc[4];
    #pragma unroll
    for(int ms=0; ms<4; ++ms) acc[ms] = (float4v)(0.f);
    #pragma unroll
    for(int kc=0; kc<4; ++kc){
      short8v aw = *(const short8v*)(wT + (size_t)(n0 + lq)*CCX + kc*32 + g*8);
      #pragma unroll
      for(int ms=0; ms<4; ++ms) acc[ms] = MFMA(aw, bx[ms][kc], acc[ms]);
    }
    #pragma unroll
    for(int ms=0; ms<4; ++ms){
      const int k = mb + ms*16 + lq;
      const int j = k & 31;
      const int kap = (k & ~31) + 8*((j>>2)&3) + 4*((j>>4)&1) + (j&3);
      #pragma unroll
      for(int r=0; r<4; ++r){
        const int d = half*16 + 4*g + r;
        const int off = d*512 + ((2*kap) ^ ((d&7)<<4));
        *(unsigned short*)(vtb + off) = __bfloat16_as_ushort(__float2bfloat16(acc[ms][r]));
      }
    }
  }
  // G -> packed bf16 regs (+bias)
  #pragma unroll
  for(int half=0; half<2; ++half){
    const int n0 = 384 + h*32 + half*16;
    float4v acc[4];
    #pragma unroll
    for(int ms=0; ms<4; ++ms) acc[ms] = (float4v)(0.f);
    #pragma unroll
    for(int kc=0; kc<4; ++kc){
      short8v aw = *(const short8v*)(wT + (size_t)(n0 + lq)*CCX + kc*32 + g*8);
      #pragma unroll
      for(int ms=0; ms<4; ++ms) acc[ms] = MFMA(aw, bx[ms][kc], acc[ms]);
    }
    const float4 bg4 = *(const float4*)(bg + h*32 + half*16 + 4*g);
    #pragma unroll
    for(int ms=0; ms<4; ++ms){
      uint2 pw; pw.x = pk2(acc[ms][0]+bg4.x, acc[ms][1]+bg4.y);
                pw.y = pk2(acc[ms][2]+bg4.z, acc[ms][3]+bg4.w);
      if(half==0) pgl[ms] = pw; else pgh[ms] = pw;
    }
  }
  __syncthreads();

  // ---- phase 2: attention, 4 static q-subtiles ----
  bf16* obh = op + ((size_t)h*NIJ + (size_t)i*NNX)*CHDX;
  const float* tbq_base = tb2 + (size_t)h*NIJ;
  attn_sub<0>(mb, lq, g, l, __builtin_bit_cast(short8v, qfr[0]), pgl[0], pgh[0], ksb, vtb, tbq_base, obh);
  attn_sub<1>(mb, lq, g, l, __builtin_bit_cast(short8v, qfr[1]), pgl[1], pgh[1], ksb, vtb, tbq_base, obh);
  attn_sub<2>(mb, lq, g, l, __builtin_bit_cast(short8v, qfr[2]), pgl[2], pgh[2], ksb, vtb, tbq_base, obh);
  attn_sub<3>(mb, lq, g, l, __builtin_bit_cast(short8v, qfr[3]), pgl[3], pgh[3], ksb, vtb, tbq_base, obh);
}

// MFMA o-projection + residual: x += o @ wo + bo. o is head-major [H][NIJ][32].
template<int TRANS>
__global__ __launch_bounds__(256) void k_oprojm(const bf16* __restrict__ ob,
    const bf16* __restrict__ woT, const float* __restrict__ bo, float* __restrict__ x){
  const int tid = threadIdx.x;
  const int w = tid >> 6, l = tid & 63;
  const int lq = l & 15, g = l >> 4;
  const int mbase = blockIdx.x*128 + w*32;
  short8v bx[2][4];
  #pragma unroll
  for(int ms=0; ms<2; ++ms){
    const size_t mrow = mbase + ms*16 + lq;
    #pragma unroll
    for(int kc=0; kc<4; ++kc)
      bx[ms][kc] = *(const short8v*)(ob + ((size_t)kc*NIJ + mrow)*CHDX + g*8);
  }
  #pragma unroll
  for(int nj=0; nj<8; ++nj){
    float4v acc0 = (float4v)(0.f), acc1 = (float4v)(0.f);
    #pragma unroll
    for(int kc=0; kc<4; ++kc){
      short8v aw = *(const short8v*)(woT + (size_t)(nj*16 + lq)*CCX + kc*32 + g*8);
      acc0 = MFMA(aw, bx[0][kc], acc0);
      acc1 = MFMA(aw, bx[1][kc], acc1);
    }
    const int col = nj*16 + 4*g;
    const float4 bo4 = *(const float4*)(bo + col);
    #pragma unroll
    for(int ms=0; ms<2; ++ms){
      const int r = mbase + ms*16 + lq;
      const int ii = r>>8, jj = r&255;
      float* dst = x + (size_t)(TRANS ? (jj*NNX+ii) : r)*CCX + col;
      float4 xv = *(float4*)dst;
      xv.x += ((ms==0)?acc0[0]:acc1[0]) + bo4.x;
      xv.y += ((ms==0)?acc0[1]:acc1[1]) + bo4.y;
      xv.z += ((ms==0)?acc0[2]:acc1[2]) + bo4.z;
      xv.w += ((ms==0)?acc0[3]:acc1[3]) + bo4.w;
      *(float4*)dst = xv;
    }
  }
}

extern "C" void kernel_launch(void* const* d_in, const int* in_sizes, int n_in,
                              void* d_out, int out_size, void* d_ws, size_t ws_size,
                              hipStream_t stream){
  const float* cmap = (const float*)d_in[0];
  char* ws = (char*)d_ws;
  float* x   = (float*)(ws);
  bf16* xln  = (bf16*)(ws + 33554432);
  bf16* ob   = (bf16*)(ws + 50331648);
  float* tb2 = (float*)(ws + 117440512);
  bf16* wT   = (bf16*)d_out;              // 160KB scratch at head of d_out; k_tout overwrites last
  bf16* woT  = wT + 65536;
  float* outp = (float*)d_out;

  for(int p=0;p<2;++p){
    const int b = 1 + 10*p;
    const float* lnw = (const float*)d_in[b+0];
    const float* lnb = (const float*)d_in[b+1];
    const float* wq  = (const float*)d_in[b+2];
    const float* wk  = (const float*)d_in[b+3];
    const float* wv  = (const float*)d_in[b+4];
    const float* wz  = (const float*)d_in[b+5];
    const float* wg  = (const float*)d_in[b+6];
    const float* bg  = (const float*)d_in[b+7];
    const float* wo  = (const float*)d_in[b+8];
    const float* bo  = (const float*)d_in[b+9];

    k_cvtw<<<320, 256, 0, stream>>>(wq, wk, wv, wg, wo, wT);

    if(p==0) k_lntin<<<dim3(8,NNX), dim3(32,8), 0, stream>>>(cmap, lnw, lnb, wz, x, xln, tb2);
    else     k_lntb<1><<<NIJ/4, dim3(64,4), 0, stream>>>(x, lnw, lnb, wz, xln, tb2);

    k_fattn<<<1024, 256, 0, stream>>>(xln, wT, bg, tb2, ob);

    if(p==0) k_oprojm<0><<<NIJ/128, 256, 0, stream>>>(ob, woT, bo, x);
    else     k_oprojm<1><<<NIJ/128, 256, 0, stream>>>(ob, woT, bo, x);
  }

  k_tout<<<dim3(8,4,NNX), dim3(32,8), 0, stream>>>(x, outp);
}